// Round 1
// baseline (12392.176 us; speedup 1.0000x reference)
//
#include <hip/hip_runtime.h>

#define TT 1024
#define BB 32
#define HH 512

typedef __attribute__((ext_vector_type(8))) __bf16 bf16x8;
typedef __attribute__((ext_vector_type(8))) short short8;
typedef __attribute__((ext_vector_type(4))) float f32x4;

union frag_u { short8 s; bf16x8 b; };

__device__ __forceinline__ unsigned short f2bf(float f) {
  unsigned int u = __float_as_uint(f);
  u += 0x7FFFu + ((u >> 16) & 1u);
  return (unsigned short)(u >> 16);
}

__device__ __forceinline__ bf16x8 cvt8(const float* p) {
  frag_u u;
#pragma unroll
  for (int j = 0; j < 8; ++j) u.s[j] = (short)f2bf(p[j]);
  return u.b;
}

__device__ __forceinline__ float sigm(float x) {
  return __builtin_amdgcn_rcpf(1.0f + __expf(-x));
}
__device__ __forceinline__ float tanh_(float x) {
  return 1.0f - 2.0f * __builtin_amdgcn_rcpf(1.0f + __expf(2.0f * x));
}

// Poll 128 per-wave flags (64 lanes x 8B) until all >= need. Monotonic flags
// (value = number of publishes) avoid same-address atomicAdd serialization.
__device__ __forceinline__ bool wait_flags(const int* flagbase, int lane, int need) {
  const long long* p = (const long long*)flagbase;
  for (int it = 0; it < (1 << 22); ++it) {
    long long v = __hip_atomic_load(p + lane, __ATOMIC_RELAXED, __HIP_MEMORY_SCOPE_AGENT);
    int a = (int)(v & 0xffffffffLL);
    int b = (int)(v >> 32);
    if (__all((a >= need) & (b >= need))) {
      __builtin_amdgcn_fence(__ATOMIC_ACQUIRE, "agent");
      return true;
    }
    __builtin_amdgcn_s_sleep(1);
  }
  return false;  // safety net against deadlock: abort wave
}

__global__ void xcvt(const float* __restrict__ x, unsigned short* __restrict__ xbf) {
  size_t i = (size_t)blockIdx.x * blockDim.x + threadIdx.x;  // 8192*256 = 2^21 = n/8 exact
  const f32x4* p = (const f32x4*)x + 2 * i;
  f32x4 a = p[0], b = p[1];
  short8 o;
  o[0] = (short)f2bf(a[0]); o[1] = (short)f2bf(a[1]);
  o[2] = (short)f2bf(a[2]); o[3] = (short)f2bf(a[3]);
  o[4] = (short)f2bf(b[0]); o[5] = (short)f2bf(b[1]);
  o[6] = (short)f2bf(b[2]); o[7] = (short)f2bf(b[3]);
  *((short8*)xbf + i) = o;
}

__global__ __launch_bounds__(64, 1) void lstm_persistent(
    const float* __restrict__ x,
    const float* __restrict__ wih0, const float* __restrict__ whh0,
    const float* __restrict__ bih0, const float* __restrict__ bhh0,
    const float* __restrict__ wih1, const float* __restrict__ whh1,
    const float* __restrict__ bih1, const float* __restrict__ bhh1,
    const float* __restrict__ h0in, const float* __restrict__ c0in,
    float* __restrict__ out,
    const unsigned short* __restrict__ xbf,  // may be null -> read x fp32 directly
    unsigned short* __restrict__ h0buf,      // [TT+1][BB][HH] bf16
    unsigned short* __restrict__ h1buf,
    int* __restrict__ flags)                 // [2][128] monotonic publish counters
{
  const int lane = threadIdx.x;            // 0..63
  const int bid = blockIdx.x;              // 0..255
  const int layer = bid >> 7;
  const int sub = bid & 127;
  const int mhalf = sub & 1;               // batch half
  const int slice = sub >> 1;              // 0..63 -> 8 h-cols each
  const int hc0 = slice << 3;
  const int q = lane >> 4;                 // MFMA quad
  const int c16 = lane & 15;               // MFMA n / m index
  const int cmod = lane & 7;
  const bool owner = (c16 < 8);
  const int mbase = mhalf << 4;
  const int waveid = layer * 128 + sub;

  const float* wih = layer ? wih1 : wih0;
  const float* whh = layer ? whh1 : whh0;
  const float* bih = layer ? bih1 : bih0;
  const float* bhh = layer ? bhh1 : bhh0;

  // gate-column map: nt0 -> {i, f}, nt1 -> {g, o} for h-cols hc0..hc0+7
  const int colN0 = owner ? (hc0 + c16) : (512 + hc0 + c16 - 8);
  const int colN1 = owner ? (1024 + hc0 + c16) : (1536 + hc0 + c16 - 8);

  // ---- persistent weight fragments: [W_ih | W_hh] bf16, 256 VGPRs ----
  bf16x8 w0[32], w1[32];
#pragma unroll
  for (int kc = 0; kc < 32; ++kc) {
    const float* s0;
    const float* s1;
    if (kc < 16) {
      s0 = wih + (size_t)colN0 * HH + kc * 32 + q * 8;
      s1 = wih + (size_t)colN1 * HH + kc * 32 + q * 8;
    } else {
      s0 = whh + (size_t)colN0 * HH + (kc - 16) * 32 + q * 8;
      s1 = whh + (size_t)colN1 * HH + (kc - 16) * 32 + q * 8;
    }
    w0[kc] = cvt8(s0);
    w1[kc] = cvt8(s1);
  }
  const float bias0 = bih[colN0] + bhh[colN0];
  const float bias1 = bih[colN1] + bhh[colN1];

  // ---- initial cell state (all lanes keep a duplicate of their pair) ----
  float creg[4];
#pragma unroll
  for (int r = 0; r < 4; ++r) {
    int batch = mbase + q * 4 + r;
    creg[r] = c0in[(size_t)layer * BB * HH + (size_t)batch * HH + hc0 + cmod];
  }

  unsigned short* myH = layer ? h1buf : h0buf;
  // publish h_0 slice (bf16)
#pragma unroll
  for (int r = 0; r < 4; ++r) {
    int batch = mbase + q * 4 + r;
    if (owner)
      myH[(size_t)batch * HH + hc0 + cmod] =
          f2bf(h0in[(size_t)layer * BB * HH + (size_t)batch * HH + hc0 + cmod]);
  }
  __builtin_amdgcn_fence(__ATOMIC_RELEASE, "agent");
  if (lane == 0)
    __hip_atomic_store(&flags[waveid], 1, __ATOMIC_RELAXED, __HIP_MEMORY_SCOPE_AGENT);

  const int* flMine = flags + layer * 128;
  const int* flL0 = flags;
  const unsigned short* inb = layer ? h0buf : xbf;

  for (int t = 1; t <= TT; ++t) {
    f32x4 acc0 = {bias0, bias0, bias0, bias0};
    f32x4 acc1 = {bias1, bias1, bias1, bias1};

    // ---- input projection part (K = 0..511) ----
    if (layer) {
      if (!wait_flags(flL0, lane, t + 1)) break;  // need h0_t
    }
    if (layer || (xbf != nullptr)) {
      const unsigned short* ip = inb + (size_t)(layer ? t : (t - 1)) * BB * HH +
                                 (size_t)(mbase + c16) * HH + q * 8;
#pragma unroll
      for (int kc = 0; kc < 16; ++kc) {
        bf16x8 a = *(const bf16x8*)(const void*)(ip + kc * 32);
        acc0 = __builtin_amdgcn_mfma_f32_16x16x32_bf16(a, w0[kc], acc0, 0, 0, 0);
        acc1 = __builtin_amdgcn_mfma_f32_16x16x32_bf16(a, w1[kc], acc1, 0, 0, 0);
      }
    } else {
      const float* ip = x + (size_t)(t - 1) * BB * HH + (size_t)(mbase + c16) * HH + q * 8;
#pragma unroll
      for (int kc = 0; kc < 16; ++kc) {
        bf16x8 a = cvt8(ip + kc * 32);
        acc0 = __builtin_amdgcn_mfma_f32_16x16x32_bf16(a, w0[kc], acc0, 0, 0, 0);
        acc1 = __builtin_amdgcn_mfma_f32_16x16x32_bf16(a, w1[kc], acc1, 0, 0, 0);
      }
    }

    // ---- recurrent part (K = 512..1023) ----
    if (!wait_flags(flMine, lane, t)) break;  // need own h_{t-1}
    {
      const unsigned short* hp = myH + (size_t)(t - 1) * BB * HH +
                                 (size_t)(mbase + c16) * HH + q * 8;
#pragma unroll
      for (int kc = 0; kc < 16; ++kc) {
        bf16x8 a = *(const bf16x8*)(const void*)(hp + kc * 32);
        acc0 = __builtin_amdgcn_mfma_f32_16x16x32_bf16(a, w0[16 + kc], acc0, 0, 0, 0);
        acc1 = __builtin_amdgcn_mfma_f32_16x16x32_bf16(a, w1[16 + kc], acc1, 0, 0, 0);
      }
    }

    // ---- elementwise: pair lanes (l <-> l^8) hold {i,g} / {f,o} ----
    float hv[4];
#pragma unroll
    for (int r = 0; r < 4; ++r) {
      float a0 = acc0[r], a1 = acc1[r];
      float p0 = __shfl_xor(a0, 8);
      float p1 = __shfl_xor(a1, 8);
      float iv = owner ? a0 : p0;
      float fv = owner ? p0 : a0;
      float gv = owner ? a1 : p1;
      float ov = owner ? p1 : a1;
      iv = sigm(iv);
      fv = sigm(fv);
      gv = tanh_(gv);
      ov = sigm(ov);
      float c = fv * creg[r] + iv * gv;
      creg[r] = c;
      hv[r] = ov * tanh_(c);
    }

    // ---- publish h_t slice (bf16) ----
    {
      unsigned short* hp = myH + (size_t)t * BB * HH;
#pragma unroll
      for (int r = 0; r < 4; ++r) {
        int batch = mbase + q * 4 + r;
        if (owner) hp[(size_t)batch * HH + hc0 + cmod] = f2bf(hv[r]);
      }
    }
    if (layer) {
      float* op = out + (size_t)(t - 1) * BB * HH;
#pragma unroll
      for (int r = 0; r < 4; ++r) {
        int batch = mbase + q * 4 + r;
        if (owner) op[(size_t)batch * HH + hc0 + cmod] = hv[r];
      }
    }
    if (t == TT) {
      float* hn = out + (size_t)TT * BB * HH + (size_t)layer * BB * HH;
      float* cn = out + (size_t)TT * BB * HH + (size_t)2 * BB * HH + (size_t)layer * BB * HH;
#pragma unroll
      for (int r = 0; r < 4; ++r) {
        int batch = mbase + q * 4 + r;
        if (owner) {
          hn[(size_t)batch * HH + hc0 + cmod] = hv[r];
          cn[(size_t)batch * HH + hc0 + cmod] = creg[r];
        }
      }
    }

    __builtin_amdgcn_fence(__ATOMIC_RELEASE, "agent");
    if (lane == 0)
      __hip_atomic_store(&flags[waveid], t + 1, __ATOMIC_RELAXED, __HIP_MEMORY_SCOPE_AGENT);
  }
}

extern "C" void kernel_launch(void* const* d_in, const int* in_sizes, int n_in,
                              void* d_out, int out_size, void* d_ws, size_t ws_size,
                              hipStream_t stream) {
  (void)in_sizes; (void)n_in; (void)out_size;
  const float* x = (const float*)d_in[0];
  const float* wih0 = (const float*)d_in[1];
  const float* whh0 = (const float*)d_in[2];
  const float* bih0 = (const float*)d_in[3];
  const float* bhh0 = (const float*)d_in[4];
  const float* wih1 = (const float*)d_in[5];
  const float* whh1 = (const float*)d_in[6];
  const float* bih1 = (const float*)d_in[7];
  const float* bhh1 = (const float*)d_in[8];
  const float* h0in = (const float*)d_in[9];
  const float* c0in = (const float*)d_in[10];
  float* out = (float*)d_out;
  char* ws = (char*)d_ws;

  const size_t xbf_bytes = (size_t)TT * BB * HH * 2;
  const size_t hbuf_bytes = (size_t)(TT + 1) * BB * HH * 2;
  int* flags = (int*)ws;
  size_t off = 4096;
  bool use_xbf = ws_size >= off + xbf_bytes + 2 * hbuf_bytes;
  unsigned short* xbf = use_xbf ? (unsigned short*)(ws + off) : nullptr;
  if (use_xbf) off += xbf_bytes;
  unsigned short* h0b = (unsigned short*)(ws + off);
  unsigned short* h1b = (unsigned short*)(ws + off + hbuf_bytes);

  hipMemsetAsync(ws, 0, 4096, stream);
  if (use_xbf) xcvt<<<dim3(8192), dim3(256), 0, stream>>>(x, xbf);
  lstm_persistent<<<dim3(256), dim3(64), 0, stream>>>(
      x, wih0, whh0, bih0, bhh0, wih1, whh1, bih1, bhh1, h0in, c0in,
      out, xbf, h0b, h1b, flags);
}

// Round 2
// 9451.651 us; speedup vs baseline: 1.3111x; 1.3111x over previous
//
#include <hip/hip_runtime.h>

#define TT 1024
#define BB 32
#define HH 512

typedef __attribute__((ext_vector_type(8))) __bf16 bf16x8;
typedef __attribute__((ext_vector_type(8))) short short8;
typedef __attribute__((ext_vector_type(4))) float f32x4;

union frag_u { short8 s; bf16x8 b; };

__device__ __forceinline__ unsigned short f2bf(float f) {
  unsigned int u = __float_as_uint(f);
  u += 0x7FFFu + ((u >> 16) & 1u);
  return (unsigned short)(u >> 16);
}

__device__ __forceinline__ bf16x8 cvt8(const float* p) {
  frag_u u;
#pragma unroll
  for (int j = 0; j < 8; ++j) u.s[j] = (short)f2bf(p[j]);
  return u.b;
}

__device__ __forceinline__ float sigm(float x) {
  return __builtin_amdgcn_rcpf(1.0f + __expf(-x));
}
__device__ __forceinline__ float tanh_(float x) {
  return 1.0f - 2.0f * __builtin_amdgcn_rcpf(1.0f + __expf(2.0f * x));
}

// Agent-coherent (sc1, bypasses stale per-XCD L2) 16B fragment load as 2x8B.
__device__ __forceinline__ bf16x8 load_h16(const unsigned short* p) {
  union { unsigned long long q[2]; bf16x8 b; } u;
  u.q[0] = __hip_atomic_load((const unsigned long long*)p,
                             __ATOMIC_RELAXED, __HIP_MEMORY_SCOPE_AGENT);
  u.q[1] = __hip_atomic_load((const unsigned long long*)(p + 4),
                             __ATOMIC_RELAXED, __HIP_MEMORY_SCOPE_AGENT);
  return u.b;
}

// Poll 128 per-wave monotonic flags (64 lanes x 8B each) until all >= need.
// No acquire fence: h is read with sc1 loads, so no cache maintenance needed.
__device__ __forceinline__ bool wait1(const int* base, int lane, int need) {
  const unsigned long long* p = (const unsigned long long*)base;
  for (int it = 0; it < (1 << 24); ++it) {
    unsigned long long v =
        __hip_atomic_load(p + lane, __ATOMIC_RELAXED, __HIP_MEMORY_SCOPE_AGENT);
    int a = (int)(v & 0xffffffffull);
    int b = (int)(v >> 32);
    if (__all((a >= need) & (b >= need))) {
      asm volatile("" ::: "memory");
      return true;
    }
  }
  return false;
}

__device__ __forceinline__ bool wait2(const int* b0, int n0, const int* b1,
                                      int n1, int lane) {
  const unsigned long long* p0 = (const unsigned long long*)b0;
  const unsigned long long* p1 = (const unsigned long long*)b1;
  for (int it = 0; it < (1 << 24); ++it) {
    unsigned long long v0 =
        __hip_atomic_load(p0 + lane, __ATOMIC_RELAXED, __HIP_MEMORY_SCOPE_AGENT);
    unsigned long long v1 =
        __hip_atomic_load(p1 + lane, __ATOMIC_RELAXED, __HIP_MEMORY_SCOPE_AGENT);
    int a0 = (int)(v0 & 0xffffffffull), c0 = (int)(v0 >> 32);
    int a1 = (int)(v1 & 0xffffffffull), c1 = (int)(v1 >> 32);
    if (__all((a0 >= n0) & (c0 >= n0) & (a1 >= n1) & (c1 >= n1))) {
      asm volatile("" ::: "memory");
      return true;
    }
  }
  return false;
}

__global__ void xcvt(const float* __restrict__ x, unsigned short* __restrict__ xbf) {
  size_t i = (size_t)blockIdx.x * blockDim.x + threadIdx.x;  // 8192*256 = n/8 exact
  const f32x4* p = (const f32x4*)x + 2 * i;
  f32x4 a = p[0], b = p[1];
  short8 o;
  o[0] = (short)f2bf(a[0]); o[1] = (short)f2bf(a[1]);
  o[2] = (short)f2bf(a[2]); o[3] = (short)f2bf(a[3]);
  o[4] = (short)f2bf(b[0]); o[5] = (short)f2bf(b[1]);
  o[6] = (short)f2bf(b[2]); o[7] = (short)f2bf(b[3]);
  *((short8*)xbf + i) = o;
}

__global__ __launch_bounds__(64, 1) void lstm_persistent(
    const float* __restrict__ x,
    const float* __restrict__ wih0, const float* __restrict__ whh0,
    const float* __restrict__ bih0, const float* __restrict__ bhh0,
    const float* __restrict__ wih1, const float* __restrict__ whh1,
    const float* __restrict__ bih1, const float* __restrict__ bhh1,
    const float* __restrict__ h0in, const float* __restrict__ c0in,
    float* __restrict__ out,
    const unsigned short* __restrict__ xbf,  // may be null -> read x fp32 directly
    unsigned short* __restrict__ h0buf,      // [TT+1][BB][HH] bf16
    unsigned short* __restrict__ h1buf,
    int* __restrict__ flags)                 // [2][128] monotonic publish counters
{
  const int lane = threadIdx.x;            // 0..63
  const int bid = blockIdx.x;              // 0..255
  const int layer = bid >> 7;
  const int sub = bid & 127;
  const int mhalf = sub & 1;               // batch half
  const int slice = sub >> 1;              // 0..63 -> 8 h-cols each
  const int hc0 = slice << 3;
  const int q = lane >> 4;                 // MFMA quad
  const int c16 = lane & 15;               // MFMA n / m index
  const int cmod = lane & 7;
  const bool owner = (c16 < 8);
  const bool pstore = owner && !(c16 & 1); // packed-pair publisher lanes
  const int mbase = mhalf << 4;
  const int waveid = layer * 128 + sub;

  const float* wih = layer ? wih1 : wih0;
  const float* whh = layer ? whh1 : whh0;
  const float* bih = layer ? bih1 : bih0;
  const float* bhh = layer ? bhh1 : bhh0;

  // gate-column map: acc0 -> {i, f}, acc1 -> {g, o} for h-cols hc0..hc0+7
  const int colN0 = owner ? (hc0 + c16) : (512 + hc0 + c16 - 8);
  const int colN1 = owner ? (1024 + hc0 + c16) : (1536 + hc0 + c16 - 8);

  // ---- persistent weight fragments: [W_ih | W_hh] bf16, 256 VGPRs ----
  bf16x8 w0[32], w1[32];
#pragma unroll
  for (int kc = 0; kc < 32; ++kc) {
    const float* s0;
    const float* s1;
    if (kc < 16) {
      s0 = wih + (size_t)colN0 * HH + kc * 32 + q * 8;
      s1 = wih + (size_t)colN1 * HH + kc * 32 + q * 8;
    } else {
      s0 = whh + (size_t)colN0 * HH + (kc - 16) * 32 + q * 8;
      s1 = whh + (size_t)colN1 * HH + (kc - 16) * 32 + q * 8;
    }
    w0[kc] = cvt8(s0);
    w1[kc] = cvt8(s1);
  }
  const float bias0 = bih[colN0] + bhh[colN0];
  const float bias1 = bih[colN1] + bhh[colN1];

  // ---- initial cell state (pair lanes keep duplicates) ----
  float creg[4];
#pragma unroll
  for (int r = 0; r < 4; ++r) {
    int batch = mbase + q * 4 + r;
    creg[r] = c0in[(size_t)layer * BB * HH + (size_t)batch * HH + hc0 + cmod];
  }

  unsigned short* myH = layer ? h1buf : h0buf;

  // ---- publish h_0 slice (bf16, packed 4B agent-coherent stores) ----
  {
    unsigned short* hp = myH;  // t = 0
#pragma unroll
    for (int r = 0; r < 4; ++r) {
      int batch = mbase + q * 4 + r;
      float hv0 = h0in[(size_t)layer * BB * HH + (size_t)batch * HH + hc0 + cmod];
      unsigned short hb = f2bf(hv0);
      unsigned int partner = (unsigned int)__shfl_xor((int)(unsigned int)hb, 1);
      unsigned int packed = ((unsigned int)hb & 0xffffu) | (partner << 16);
      if (pstore) {
        unsigned int* dst = (unsigned int*)(hp + (size_t)batch * HH + hc0 + cmod);
        __hip_atomic_store(dst, packed, __ATOMIC_RELAXED, __HIP_MEMORY_SCOPE_AGENT);
      }
    }
  }
  asm volatile("s_waitcnt vmcnt(0)" ::: "memory");
  if (lane == 0)
    __hip_atomic_store(&flags[waveid], 1, __ATOMIC_RELAXED, __HIP_MEMORY_SCOPE_AGENT);

  const int* flMine = flags + layer * 128;
  const int* flL0 = flags;
  const unsigned short* inb = layer ? h0buf : xbf;

  for (int t = 1; t <= TT; ++t) {
    f32x4 acc0 = {bias0, bias0, bias0, bias0};
    f32x4 acc1 = {bias1, bias1, bias1, bias1};

    if (layer == 0) {
      // ---- input projection (xbf, L2-cached normal loads), before the wait ----
      if (xbf != nullptr) {
        const unsigned short* ip = inb + (size_t)(t - 1) * BB * HH +
                                   (size_t)(mbase + c16) * HH + q * 8;
#pragma unroll
        for (int kc = 0; kc < 16; ++kc) {
          bf16x8 a = *(const bf16x8*)(const void*)(ip + kc * 32);
          acc0 = __builtin_amdgcn_mfma_f32_16x16x32_bf16(a, w0[kc], acc0, 0, 0, 0);
          acc1 = __builtin_amdgcn_mfma_f32_16x16x32_bf16(a, w1[kc], acc1, 0, 0, 0);
        }
      } else {
        const float* ip = x + (size_t)(t - 1) * BB * HH + (size_t)(mbase + c16) * HH + q * 8;
#pragma unroll
        for (int kc = 0; kc < 16; ++kc) {
          bf16x8 a = cvt8(ip + kc * 32);
          acc0 = __builtin_amdgcn_mfma_f32_16x16x32_bf16(a, w0[kc], acc0, 0, 0, 0);
          acc1 = __builtin_amdgcn_mfma_f32_16x16x32_bf16(a, w1[kc], acc1, 0, 0, 0);
        }
      }
      if (!wait1(flMine, lane, t)) break;  // need own h_{t-1}
    } else {
      // layer 1: need h0_t (flag t+1) and own h1_{t-1} (flag t) — one combined poll
      if (!wait2(flL0, t + 1, flMine, t, lane)) break;
      const unsigned short* ip = inb + (size_t)t * BB * HH +
                                 (size_t)(mbase + c16) * HH + q * 8;
#pragma unroll
      for (int kc = 0; kc < 16; ++kc) {
        bf16x8 a = load_h16(ip + kc * 32);
        acc0 = __builtin_amdgcn_mfma_f32_16x16x32_bf16(a, w0[kc], acc0, 0, 0, 0);
        acc1 = __builtin_amdgcn_mfma_f32_16x16x32_bf16(a, w1[kc], acc1, 0, 0, 0);
      }
    }

    // ---- recurrent part (K = 512..1023), agent-coherent loads ----
    {
      const unsigned short* hp = myH + (size_t)(t - 1) * BB * HH +
                                 (size_t)(mbase + c16) * HH + q * 8;
#pragma unroll
      for (int kc = 0; kc < 16; ++kc) {
        bf16x8 a = load_h16(hp + kc * 32);
        acc0 = __builtin_amdgcn_mfma_f32_16x16x32_bf16(a, w0[16 + kc], acc0, 0, 0, 0);
        acc1 = __builtin_amdgcn_mfma_f32_16x16x32_bf16(a, w1[16 + kc], acc1, 0, 0, 0);
      }
    }

    // ---- elementwise: pair lanes (l <-> l^8) hold {i,g} / {f,o} ----
    float hv[4];
#pragma unroll
    for (int r = 0; r < 4; ++r) {
      float a0 = acc0[r], a1 = acc1[r];
      float p0 = __shfl_xor(a0, 8);
      float p1 = __shfl_xor(a1, 8);
      float iv = owner ? a0 : p0;
      float fv = owner ? p0 : a0;
      float gv = owner ? a1 : p1;
      float ov = owner ? p1 : a1;
      iv = sigm(iv);
      fv = sigm(fv);
      gv = tanh_(gv);
      ov = sigm(ov);
      float c = fv * creg[r] + iv * gv;
      creg[r] = c;
      hv[r] = ov * tanh_(c);
    }

    // ---- publish h_t slice: packed 4B agent-coherent stores, then flag ----
    {
      unsigned short* hp = myH + (size_t)t * BB * HH;
#pragma unroll
      for (int r = 0; r < 4; ++r) {
        int batch = mbase + q * 4 + r;
        unsigned short hb = f2bf(hv[r]);
        unsigned int partner = (unsigned int)__shfl_xor((int)(unsigned int)hb, 1);
        unsigned int packed = ((unsigned int)hb & 0xffffu) | (partner << 16);
        if (pstore) {
          unsigned int* dst = (unsigned int*)(hp + (size_t)batch * HH + hc0 + cmod);
          __hip_atomic_store(dst, packed, __ATOMIC_RELAXED, __HIP_MEMORY_SCOPE_AGENT);
        }
      }
    }
    asm volatile("s_waitcnt vmcnt(0)" ::: "memory");
    if (lane == 0)
      __hip_atomic_store(&flags[waveid], t + 1, __ATOMIC_RELAXED, __HIP_MEMORY_SCOPE_AGENT);

    // ---- off-critical-path outputs (normal cached stores) ----
    if (layer) {
      float* op = out + (size_t)(t - 1) * BB * HH;
#pragma unroll
      for (int r = 0; r < 4; ++r) {
        int batch = mbase + q * 4 + r;
        if (owner) op[(size_t)batch * HH + hc0 + cmod] = hv[r];
      }
    }
    if (t == TT) {
      float* hn = out + (size_t)TT * BB * HH + (size_t)layer * BB * HH;
      float* cn = out + (size_t)TT * BB * HH + (size_t)2 * BB * HH + (size_t)layer * BB * HH;
#pragma unroll
      for (int r = 0; r < 4; ++r) {
        int batch = mbase + q * 4 + r;
        if (owner) {
          hn[(size_t)batch * HH + hc0 + cmod] = hv[r];
          cn[(size_t)batch * HH + hc0 + cmod] = creg[r];
        }
      }
    }
  }
}

extern "C" void kernel_launch(void* const* d_in, const int* in_sizes, int n_in,
                              void* d_out, int out_size, void* d_ws, size_t ws_size,
                              hipStream_t stream) {
  (void)in_sizes; (void)n_in; (void)out_size;
  const float* x = (const float*)d_in[0];
  const float* wih0 = (const float*)d_in[1];
  const float* whh0 = (const float*)d_in[2];
  const float* bih0 = (const float*)d_in[3];
  const float* bhh0 = (const float*)d_in[4];
  const float* wih1 = (const float*)d_in[5];
  const float* whh1 = (const float*)d_in[6];
  const float* bih1 = (const float*)d_in[7];
  const float* bhh1 = (const float*)d_in[8];
  const float* h0in = (const float*)d_in[9];
  const float* c0in = (const float*)d_in[10];
  float* out = (float*)d_out;
  char* ws = (char*)d_ws;

  const size_t xbf_bytes = (size_t)TT * BB * HH * 2;
  const size_t hbuf_bytes = (size_t)(TT + 1) * BB * HH * 2;
  int* flags = (int*)ws;
  size_t off = 4096;
  bool use_xbf = ws_size >= off + xbf_bytes + 2 * hbuf_bytes;
  unsigned short* xbf = use_xbf ? (unsigned short*)(ws + off) : nullptr;
  if (use_xbf) off += xbf_bytes;
  unsigned short* h0b = (unsigned short*)(ws + off);
  unsigned short* h1b = (unsigned short*)(ws + off + hbuf_bytes);

  hipMemsetAsync(ws, 0, 4096, stream);
  if (use_xbf) xcvt<<<dim3(8192), dim3(256), 0, stream>>>(x, xbf);
  lstm_persistent<<<dim3(256), dim3(64), 0, stream>>>(
      x, wih0, whh0, bih0, bhh0, wih1, whh1, bih1, bhh1, h0in, c0in,
      out, xbf, h0b, h1b, flags);
}

// Round 4
// 7949.841 us; speedup vs baseline: 1.5588x; 1.1889x over previous
//
#include <hip/hip_runtime.h>

#define TT 1024
#define BB 32
#define HH 512

typedef __attribute__((ext_vector_type(8))) __bf16 bf16x8;
typedef __attribute__((ext_vector_type(8))) short short8;
typedef __attribute__((ext_vector_type(4))) float f32x4;

union frag_u { short8 s; bf16x8 b; f32x4 f; unsigned long long q[2]; };

__device__ __forceinline__ unsigned short f2bf(float f) {
  unsigned int u = __float_as_uint(f);
  u += 0x7FFFu + ((u >> 16) & 1u);
  return (unsigned short)(u >> 16);
}

__device__ __forceinline__ bf16x8 cvt8(const float* p) {
  frag_u u;
#pragma unroll
  for (int j = 0; j < 8; ++j) u.s[j] = (short)f2bf(p[j]);
  return u.b;
}

__device__ __forceinline__ float sigm(float x) {
  return __builtin_amdgcn_rcpf(1.0f + __expf(-x));
}
__device__ __forceinline__ float tanh_(float x) {
  return 1.0f - 2.0f * __builtin_amdgcn_rcpf(1.0f + __expf(2.0f * x));
}

__device__ __forceinline__ void wait_vm0() {
  asm volatile("s_waitcnt vmcnt(0)" ::: "memory");
}

__device__ __forceinline__ unsigned long long aload(const unsigned long long* p) {
  return __hip_atomic_load(p, __ATOMIC_RELAXED, __HIP_MEMORY_SCOPE_AGENT);
}

// Poll 128 per-wave monotonic flags (64 lanes x 8B) until all >= need.
__device__ __forceinline__ bool wait1(const int* base, int lane, int need) {
  const unsigned long long* p = (const unsigned long long*)base;
  for (int it = 0; it < (1 << 24); ++it) {
    unsigned long long v = aload(p + lane);
    int a = (int)(v & 0xffffffffull);
    int b = (int)(v >> 32);
    if (__all((a >= need) & (b >= need))) {
      asm volatile("" ::: "memory");
      return true;
    }
  }
  return false;
}

__device__ __forceinline__ bool wait2(const int* b0, int n0, const int* b1,
                                      int n1, int lane) {
  const unsigned long long* p0 = (const unsigned long long*)b0;
  const unsigned long long* p1 = (const unsigned long long*)b1;
  for (int it = 0; it < (1 << 24); ++it) {
    unsigned long long v0 = aload(p0 + lane);
    unsigned long long v1 = aload(p1 + lane);
    int a0 = (int)(v0 & 0xffffffffull), c0 = (int)(v0 >> 32);
    int a1 = (int)(v1 & 0xffffffffull), c1 = (int)(v1 >> 32);
    if (__all((a0 >= n0) & (c0 >= n0) & (a1 >= n1) & (c1 >= n1))) {
      asm volatile("" ::: "memory");
      return true;
    }
  }
  return false;
}

__global__ void xcvt(const float* __restrict__ x, unsigned short* __restrict__ xbf) {
  size_t i = (size_t)blockIdx.x * blockDim.x + threadIdx.x;  // 8192*256 = n/8 exact
  const f32x4* p = (const f32x4*)x + 2 * i;
  f32x4 a = p[0], b = p[1];
  short8 o;
  o[0] = (short)f2bf(a[0]); o[1] = (short)f2bf(a[1]);
  o[2] = (short)f2bf(a[2]); o[3] = (short)f2bf(a[3]);
  o[4] = (short)f2bf(b[0]); o[5] = (short)f2bf(b[1]);
  o[6] = (short)f2bf(b[2]); o[7] = (short)f2bf(b[3]);
  *((short8*)xbf + i) = o;
}

__global__ __launch_bounds__(64, 1) void lstm_persistent(
    const float* __restrict__ x,
    const float* __restrict__ wih0, const float* __restrict__ whh0,
    const float* __restrict__ bih0, const float* __restrict__ bhh0,
    const float* __restrict__ wih1, const float* __restrict__ whh1,
    const float* __restrict__ bih1, const float* __restrict__ bhh1,
    const float* __restrict__ h0in, const float* __restrict__ c0in,
    float* __restrict__ out,
    const unsigned short* __restrict__ xbf,  // may be null -> read x fp32 directly
    unsigned short* __restrict__ h0buf,      // [TT+1][BB][HH] bf16
    unsigned short* __restrict__ h1buf,
    int* __restrict__ flags)                 // [2][128] monotonic publish counters
{
  const int lane = threadIdx.x;            // 0..63
  const int bid = blockIdx.x;              // 0..255
  const int layer = bid >> 7;
  const int sub = bid & 127;
  const int mhalf = sub & 1;               // batch half
  const int slice = sub >> 1;              // 0..63 -> 8 h-cols each
  const int hc0 = slice << 3;
  const int q = lane >> 4;                 // MFMA quad
  const int c16 = lane & 15;               // MFMA n / m index
  const int cmod = lane & 7;
  const bool owner = (c16 < 8);
  const bool pstore = owner && !(c16 & 1); // packed-pair publisher lanes
  const int mbase = mhalf << 4;
  const int waveid = layer * 128 + sub;

  const float* wih = layer ? wih1 : wih0;
  const float* whh = layer ? whh1 : whh0;
  const float* bih = layer ? bih1 : bih0;
  const float* bhh = layer ? bhh1 : bhh0;

  // gate-column map: acc0 -> {i, f}, acc1 -> {g, o} for h-cols hc0..hc0+7
  const int colN0 = owner ? (hc0 + c16) : (512 + hc0 + c16 - 8);
  const int colN1 = owner ? (1024 + hc0 + c16) : (1536 + hc0 + c16 - 8);

  // ---- persistent weight fragments: [W_ih | W_hh] bf16, 256 VGPRs ----
  bf16x8 w0[32], w1[32];
#pragma unroll
  for (int kc = 0; kc < 32; ++kc) {
    const float* s0;
    const float* s1;
    if (kc < 16) {
      s0 = wih + (size_t)colN0 * HH + kc * 32 + q * 8;
      s1 = wih + (size_t)colN1 * HH + kc * 32 + q * 8;
    } else {
      s0 = whh + (size_t)colN0 * HH + (kc - 16) * 32 + q * 8;
      s1 = whh + (size_t)colN1 * HH + (kc - 16) * 32 + q * 8;
    }
    w0[kc] = cvt8(s0);
    w1[kc] = cvt8(s1);
  }
  const float bias0 = bih[colN0] + bhh[colN0];
  const float bias1 = bih[colN1] + bhh[colN1];

  // ---- initial cell state (pair lanes keep duplicates) ----
  float creg[4];
#pragma unroll
  for (int r = 0; r < 4; ++r) {
    int batch = mbase + q * 4 + r;
    creg[r] = c0in[(size_t)layer * BB * HH + (size_t)batch * HH + hc0 + cmod];
  }

  unsigned short* myH = layer ? h1buf : h0buf;

  // ---- publish h_0 slice (bf16, packed 4B agent-coherent stores) ----
  {
    unsigned short* hp = myH;  // t = 0
#pragma unroll
    for (int r = 0; r < 4; ++r) {
      int batch = mbase + q * 4 + r;
      float hv0 = h0in[(size_t)layer * BB * HH + (size_t)batch * HH + hc0 + cmod];
      unsigned short hb = f2bf(hv0);
      unsigned int partner = (unsigned int)__shfl_xor((int)(unsigned int)hb, 1);
      unsigned int packed = ((unsigned int)hb & 0xffffu) | (partner << 16);
      if (pstore) {
        unsigned int* dst = (unsigned int*)(hp + (size_t)batch * HH + hc0 + cmod);
        __hip_atomic_store(dst, packed, __ATOMIC_RELAXED, __HIP_MEMORY_SCOPE_AGENT);
      }
    }
  }
  wait_vm0();
  if (lane == 0)
    __hip_atomic_store(&flags[waveid], 1, __ATOMIC_RELAXED, __HIP_MEMORY_SCOPE_AGENT);

  const int* flMine = flags + layer * 128;
  const int* flL0 = flags;

  const size_t laneoff = (size_t)(mbase + c16) * HH + q * 8;  // shorts

  for (int t = 1; t <= TT; ++t) {
    f32x4 acc0 = {bias0, bias0, bias0, bias0};
    f32x4 acc1 = {bias1, bias1, bias1, bias1};

    if (layer == 0) {
      // ---- input projection (xbf, L2-cached normal loads), before the wait ----
      if (xbf != nullptr) {
        const unsigned short* ip = xbf + (size_t)(t - 1) * BB * HH + laneoff;
#pragma unroll
        for (int kc = 0; kc < 16; ++kc) {
          bf16x8 a = *(const bf16x8*)(const void*)(ip + kc * 32);
          acc0 = __builtin_amdgcn_mfma_f32_16x16x32_bf16(a, w0[kc], acc0, 0, 0, 0);
          acc1 = __builtin_amdgcn_mfma_f32_16x16x32_bf16(a, w1[kc], acc1, 0, 0, 0);
        }
      } else {
        const float* ip = x + (size_t)(t - 1) * BB * HH + laneoff;
#pragma unroll
        for (int kc = 0; kc < 16; ++kc) {
          bf16x8 a = cvt8(ip + kc * 32);
          acc0 = __builtin_amdgcn_mfma_f32_16x16x32_bf16(a, w0[kc], acc0, 0, 0, 0);
          acc1 = __builtin_amdgcn_mfma_f32_16x16x32_bf16(a, w1[kc], acc1, 0, 0, 0);
        }
      }
      if (!wait1(flMine, lane, t)) break;  // need own h_{t-1}

      // ---- recurrent part: issue ALL 32 coherent 8B loads, then consume ----
      const unsigned long long* q0 =
          (const unsigned long long*)(myH + (size_t)(t - 1) * BB * HH + laneoff);
      unsigned long long hq[32];
#pragma unroll
      for (int kc = 0; kc < 16; ++kc) {
        hq[2 * kc] = aload(q0 + kc * 8);
        hq[2 * kc + 1] = aload(q0 + kc * 8 + 1);
      }
#pragma unroll
      for (int kc = 0; kc < 16; ++kc) {
        frag_u u;
        u.q[0] = hq[2 * kc];
        u.q[1] = hq[2 * kc + 1];
        acc0 = __builtin_amdgcn_mfma_f32_16x16x32_bf16(u.b, w0[16 + kc], acc0, 0, 0, 0);
        acc1 = __builtin_amdgcn_mfma_f32_16x16x32_bf16(u.b, w1[16 + kc], acc1, 0, 0, 0);
      }
    } else {
      // layer 1: need h0_t (flag t+1) and own h1_{t-1} (flag t)
      if (!wait2(flL0, t + 1, flMine, t, lane)) break;
      const unsigned long long* qa =
          (const unsigned long long*)(h0buf + (size_t)t * BB * HH + laneoff);
      const unsigned long long* qb =
          (const unsigned long long*)(h1buf + (size_t)(t - 1) * BB * HH + laneoff);
      unsigned long long fa[32], fb[32];
#pragma unroll
      for (int kc = 0; kc < 16; ++kc) {
        fa[2 * kc] = aload(qa + kc * 8);
        fa[2 * kc + 1] = aload(qa + kc * 8 + 1);
      }
#pragma unroll
      for (int kc = 0; kc < 16; ++kc) {
        fb[2 * kc] = aload(qb + kc * 8);
        fb[2 * kc + 1] = aload(qb + kc * 8 + 1);
      }
#pragma unroll
      for (int kc = 0; kc < 16; ++kc) {
        frag_u u;
        u.q[0] = fa[2 * kc];
        u.q[1] = fa[2 * kc + 1];
        acc0 = __builtin_amdgcn_mfma_f32_16x16x32_bf16(u.b, w0[kc], acc0, 0, 0, 0);
        acc1 = __builtin_amdgcn_mfma_f32_16x16x32_bf16(u.b, w1[kc], acc1, 0, 0, 0);
      }
#pragma unroll
      for (int kc = 0; kc < 16; ++kc) {
        frag_u u;
        u.q[0] = fb[2 * kc];
        u.q[1] = fb[2 * kc + 1];
        acc0 = __builtin_amdgcn_mfma_f32_16x16x32_bf16(u.b, w0[16 + kc], acc0, 0, 0, 0);
        acc1 = __builtin_amdgcn_mfma_f32_16x16x32_bf16(u.b, w1[16 + kc], acc1, 0, 0, 0);
      }
    }

    // ---- elementwise: pair lanes (l <-> l^8) hold {i,g} / {f,o} ----
    float hv[4];
#pragma unroll
    for (int r = 0; r < 4; ++r) {
      float a0 = acc0[r], a1 = acc1[r];
      float p0 = __shfl_xor(a0, 8);
      float p1 = __shfl_xor(a1, 8);
      float iv = owner ? a0 : p0;
      float fv = owner ? p0 : a0;
      float gv = owner ? a1 : p1;
      float ov = owner ? p1 : a1;
      iv = sigm(iv);
      fv = sigm(fv);
      gv = tanh_(gv);
      ov = sigm(ov);
      float c = fv * creg[r] + iv * gv;
      creg[r] = c;
      hv[r] = ov * tanh_(c);
    }

    // ---- publish h_t slice: packed 4B agent-coherent stores, drain, flag ----
    {
      unsigned short* hp = myH + (size_t)t * BB * HH;
#pragma unroll
      for (int r = 0; r < 4; ++r) {
        int batch = mbase + q * 4 + r;
        unsigned short hb = f2bf(hv[r]);
        unsigned int partner = (unsigned int)__shfl_xor((int)(unsigned int)hb, 1);
        unsigned int packed = ((unsigned int)hb & 0xffffu) | (partner << 16);
        if (pstore) {
          unsigned int* dst = (unsigned int*)(hp + (size_t)batch * HH + hc0 + cmod);
          __hip_atomic_store(dst, packed, __ATOMIC_RELAXED, __HIP_MEMORY_SCOPE_AGENT);
        }
      }
    }
    wait_vm0();
    if (lane == 0)
      __hip_atomic_store(&flags[waveid], t + 1, __ATOMIC_RELAXED, __HIP_MEMORY_SCOPE_AGENT);

    // ---- off-critical-path outputs (normal cached stores) ----
    if (layer) {
      float* op = out + (size_t)(t - 1) * BB * HH;
#pragma unroll
      for (int r = 0; r < 4; ++r) {
        int batch = mbase + q * 4 + r;
        if (owner) op[(size_t)batch * HH + hc0 + cmod] = hv[r];
      }
    }
    if (t == TT) {
      float* hn = out + (size_t)TT * BB * HH + (size_t)layer * BB * HH;
      float* cn = out + (size_t)TT * BB * HH + (size_t)2 * BB * HH + (size_t)layer * BB * HH;
#pragma unroll
      for (int r = 0; r < 4; ++r) {
        int batch = mbase + q * 4 + r;
        if (owner) {
          hn[(size_t)batch * HH + hc0 + cmod] = hv[r];
          cn[(size_t)batch * HH + hc0 + cmod] = creg[r];
        }
      }
    }
  }
}

extern "C" void kernel_launch(void* const* d_in, const int* in_sizes, int n_in,
                              void* d_out, int out_size, void* d_ws, size_t ws_size,
                              hipStream_t stream) {
  (void)in_sizes; (void)n_in; (void)out_size;
  const float* x = (const float*)d_in[0];
  const float* wih0 = (const float*)d_in[1];
  const float* whh0 = (const float*)d_in[2];
  const float* bih0 = (const float*)d_in[3];
  const float* bhh0 = (const float*)d_in[4];
  const float* wih1 = (const float*)d_in[5];
  const float* whh1 = (const float*)d_in[6];
  const float* bih1 = (const float*)d_in[7];
  const float* bhh1 = (const float*)d_in[8];
  const float* h0in = (const float*)d_in[9];
  const float* c0in = (const float*)d_in[10];
  float* out = (float*)d_out;
  char* ws = (char*)d_ws;

  const size_t xbf_bytes = (size_t)TT * BB * HH * 2;
  const size_t hbuf_bytes = (size_t)(TT + 1) * BB * HH * 2;
  int* flags = (int*)ws;
  size_t off = 4096;
  bool use_xbf = ws_size >= off + xbf_bytes + 2 * hbuf_bytes;
  unsigned short* xbf = use_xbf ? (unsigned short*)(ws + off) : nullptr;
  if (use_xbf) off += xbf_bytes;
  unsigned short* h0b = (unsigned short*)(ws + off);
  unsigned short* h1b = (unsigned short*)(ws + off + hbuf_bytes);

  hipMemsetAsync(ws, 0, 4096, stream);
  if (use_xbf) xcvt<<<dim3(8192), dim3(256), 0, stream>>>(x, xbf);
  lstm_persistent<<<dim3(256), dim3(64), 0, stream>>>(
      x, wih0, whh0, bih0, bhh0, wih1, whh1, bih1, bhh1, h0in, c0in,
      out, xbf, h0b, h1b, flags);
}